// Round 7
// baseline (1284.694 us; speedup 1.0000x reference)
//
#include <hip/hip_runtime.h>
#include <hip/hip_bf16.h>

// ---------------------------------------------------------------------------
// 2-layer GCN via dst-range bucketing (no per-node CSR, no f32 global atomics
// on the hot path):
//   deg[i] = 1 + indeg(i);  dis[i] = rsqrt(deg[i])
//   layer: out[i] = dis[i]*(dis[i]*h[i] + sum_{e:dst=i} dis[src]*h[src])
// Pass A: partition edges into 512 dst-range buckets (coalesced LDS-staged
//         flushes). Built once, used by both layers.
// Pass B: per-bucket LDS accumulator (196 nodes x 16 cols), edge-parallel
//         gathers + LDS atomics, coalesced epilogue.
// ---------------------------------------------------------------------------

#define N_NODES 100000
#define F_IN 512
#define F_OUT 16
#define NB 512          // buckets
#define RNG 196         // nodes per bucket (ceil(100000/512)); dl fits 8 bits
#define QCAP 24         // LDS queue slots per bucket in pass A
#define WS_PAD 516      // gemm1 LDS pad

// ---- zero int buffer ------------------------------------------------------
__global__ void k_zero_i32(int* __restrict__ p, int n) {
    int i = blockIdx.x * blockDim.x + threadIdx.x;
    if (i < n) p[i] = 0;
}

// ---- in-degree histogram --------------------------------------------------
__global__ void k_hist(const int* __restrict__ dst, int* __restrict__ deg, int E) {
    int e = blockIdx.x * blockDim.x + threadIdx.x;
    if (e < E) atomicAdd(&deg[dst[e]], 1);
}

// ---- dis = rsqrt(1 + deg) -------------------------------------------------
__global__ void k_dis(const int* __restrict__ deg, float* __restrict__ dis, int n) {
    int i = blockIdx.x * blockDim.x + threadIdx.x;
    if (i < n) dis[i] = rsqrtf(1.0f + (float)deg[i]);
}

// ---- per-bucket edge counts: bcnt[b] = sum deg over node range ------------
__global__ void k_bucket_count(const int* __restrict__ deg, int* __restrict__ bcnt, int n) {
    int b = blockIdx.x * blockDim.x + threadIdx.x;
    if (b >= NB) return;
    int beg = b * RNG, end = min(n, beg + RNG);
    int sum = 0;
    for (int i = beg; i < end; ++i) sum += deg[i];
    bcnt[b] = (beg < n) ? sum : 0;
}

// ---- exclusive scan of 512 bucket counts -> bbase[513], cur[512] ----------
__global__ __launch_bounds__(512) void k_scan_buckets(const int* __restrict__ bcnt,
                                                      int* __restrict__ bbase,
                                                      int* __restrict__ cur) {
    __shared__ int s[NB];
    int i = threadIdx.x;
    int v = bcnt[i];
    s[i] = v;
    __syncthreads();
#pragma unroll
    for (int off = 1; off < NB; off <<= 1) {
        int t = (i >= off) ? s[i - off] : 0;
        __syncthreads();
        s[i] += t;
        __syncthreads();
    }
    int excl = s[i] - v;
    bbase[i] = excl;
    cur[i] = excl;
    if (i == NB - 1) bbase[NB] = s[NB - 1];   // total = E
}

// ---- Pass A: partition edges into bucket-clustered ebuf -------------------
// entry = src | (dst_local << 17)  (src<2^17, dst_local<196<2^8)
__global__ __launch_bounds__(256) void k_partition(const int* __restrict__ src,
                                                   const int* __restrict__ dst,
                                                   int* __restrict__ cur,
                                                   unsigned* __restrict__ ebuf,
                                                   int E, int per) {
    __shared__ unsigned q[NB][QCAP];   // 48 KB
    __shared__ int qc[NB];             //  2 KB
    for (int i = threadIdx.x; i < NB; i += 256) qc[i] = 0;
    __syncthreads();

    int beg = blockIdx.x * per;
    int end = min(E, beg + per);
    for (int e = beg + threadIdx.x; e < end; e += 256) {
        int s = src[e], d = dst[e];
        int b = d / RNG;                          // magic-mul div by constant
        unsigned ent = (unsigned)s | ((unsigned)(d - b * RNG) << 17);
        int c = atomicAdd(&qc[b], 1);
        if (c < QCAP) q[b][c] = ent;
        else ebuf[atomicAdd(&cur[b], 1)] = ent;   // rare overflow: direct write
    }
    __syncthreads();

    // flush: 16 groups of 16 lanes; coalesced per-bucket bursts
    int g = threadIdx.x >> 4, l = threadIdx.x & 15;
    for (int b = g; b < NB; b += 16) {
        int c = qc[b];
        if (c > QCAP) c = QCAP;
        if (c == 0) continue;
        int base = 0;
        if (l == 0) base = atomicAdd(&cur[b], c);
        base = __shfl(base, 0, 16);
        for (int i = l; i < c; i += 16) ebuf[base + i] = q[b][i];
    }
}

// ---- Pass B: per-bucket aggregation, self-loop fused ----------------------
__global__ __launch_bounds__(512) void k_agg_bucket(const unsigned* __restrict__ ebuf,
                                                    const int* __restrict__ bbase,
                                                    const float* __restrict__ dis,
                                                    const float* __restrict__ h,
                                                    float* __restrict__ out, int n) {
    __shared__ float acc[RNG * 16];    // 12.25 KB
    for (int i = threadIdx.x; i < RNG * 16; i += 512) acc[i] = 0.0f;
    __syncthreads();

    int b = blockIdx.x;
    int beg = bbase[b], end = bbase[b + 1];
    int g = threadIdx.x >> 4, l = threadIdx.x & 15;   // 32 groups x 16 lanes

    // edge-parallel, unrolled x2 for gather ILP
    for (int idx = beg + g; idx < end; idx += 64) {
        unsigned e0 = ebuf[idx];
        int s0 = e0 & 0x1FFFF;
        int d0 = e0 >> 17;
        float w0 = dis[s0];
        float h0 = h[(size_t)s0 * 16 + l];
        int i1 = idx + 32;
        if (i1 < end) {
            unsigned e1 = ebuf[i1];
            int s1 = e1 & 0x1FFFF;
            int d1 = e1 >> 17;
            float w1 = dis[s1];
            float h1v = h[(size_t)s1 * 16 + l];
            atomicAdd(&acc[d0 * 16 + l], w0 * h0);
            atomicAdd(&acc[d1 * 16 + l], w1 * h1v);
        } else {
            atomicAdd(&acc[d0 * 16 + l], w0 * h0);
        }
    }
    __syncthreads();

    // epilogue: out = dd*(dd*h + acc), coalesced
    int base_node = b * RNG;
    for (int nl = g; nl < RNG; nl += 32) {
        int node = base_node + nl;
        if (node < n) {
            float dd = dis[node];
            size_t o = (size_t)node * 16 + l;
            out[o] = dd * (dd * h[o] + acc[nl * 16 + l]);
        }
    }
}

// ---- GEMM1: h[N,16] = x[N,512] @ W[512,16], shfl-broadcast ----------------
__global__ __launch_bounds__(256) void k_gemm1(const float* __restrict__ x,
                                               const float* __restrict__ W,
                                               float* __restrict__ h, int nrows) {
    __shared__ __align__(16) float Ws[F_OUT * WS_PAD];  // ~33 KB
    for (int i = threadIdx.x; i < F_IN * F_OUT; i += 256) {
        int k = i >> 4, o = i & 15;
        Ws[o * WS_PAD + k] = W[i];                      // WsT[o][k] = W[k][o]
    }
    __syncthreads();

    int l = threadIdx.x & 15;
    int r = blockIdx.x * 16 + (threadIdx.x >> 4);
    if (r >= nrows) return;

    const float4* xr = (const float4*)(x + (size_t)r * F_IN);
    float4 v[8];
#pragma unroll
    for (int c = 0; c < 8; ++c) v[c] = xr[c * 16 + l];  // coalesced, 1/16 the loads

    const float* wrow = Ws + l * WS_PAD;
    float acc = 0.0f;
#pragma unroll
    for (int c = 0; c < 8; ++c) {
#pragma unroll
        for (int t = 0; t < 16; ++t) {
            float4 wv = *(const float4*)(wrow + c * 64 + t * 4);
            float ax = __shfl(v[c].x, t, 16);
            float ay = __shfl(v[c].y, t, 16);
            float az = __shfl(v[c].z, t, 16);
            float aw = __shfl(v[c].w, t, 16);
            acc = fmaf(ax, wv.x, acc);
            acc = fmaf(ay, wv.y, acc);
            acc = fmaf(az, wv.z, acc);
            acc = fmaf(aw, wv.w, acc);
        }
    }
    h[(size_t)r * 16 + l] = acc;
}

// ---- small GEMM2: h2[N,16] = a[N,16] @ W2[16,16] --------------------------
__global__ __launch_bounds__(256) void k_gemm2(const float* __restrict__ a,
                                               const float* __restrict__ W,
                                               float* __restrict__ h2, int nrows) {
    __shared__ float Ws[F_OUT * 17];
    if (threadIdx.x < 256) {
        int i = threadIdx.x;
        int k = i >> 4, o = i & 15;
        Ws[o * 17 + k] = W[i];
    }
    __syncthreads();
    int l = threadIdx.x & 15;
    int r = blockIdx.x * 16 + (threadIdx.x >> 4);
    if (r >= nrows) return;
    float av = a[(size_t)r * 16 + l];
    const float* wrow = Ws + l * 17;
    float acc = 0.0f;
#pragma unroll
    for (int t = 0; t < 16; ++t) {
        float xv = __shfl(av, t, 16);
        acc = fmaf(xv, wrow[t], acc);
    }
    h2[(size_t)r * 16 + l] = acc;
}

// ---------------- fallback path (atomic scatter), proven correct -----------
__global__ void k_deg_init(float* __restrict__ deg, int n) {
    int i = blockIdx.x * blockDim.x + threadIdx.x;
    if (i < n) deg[i] = 1.0f;
}
__global__ void k_deg_count(const int* __restrict__ dst, float* __restrict__ deg, int E) {
    int e = blockIdx.x * blockDim.x + threadIdx.x;
    if (e < E) unsafeAtomicAdd(&deg[dst[e]], 1.0f);
}
__global__ void k_rsqrt(float* __restrict__ deg, int n) {
    int i = blockIdx.x * blockDim.x + threadIdx.x;
    if (i < n) deg[i] = rsqrtf(deg[i]);
}
__global__ void k_selfloop_init(const float* __restrict__ dis, const float* __restrict__ h,
                                float* __restrict__ out, int total) {
    int t = blockIdx.x * blockDim.x + threadIdx.x;
    if (t >= total) return;
    int i = t >> 4;
    float d = dis[i];
    out[t] = d * d * h[t];
}
__global__ __launch_bounds__(256) void k_scatter(const int* __restrict__ src,
                                                 const int* __restrict__ dst,
                                                 const float* __restrict__ dis,
                                                 const float* __restrict__ h,
                                                 float* __restrict__ out, int E) {
    int gid = blockIdx.x * 256 + threadIdx.x;
    int e = gid >> 4;
    if (e >= E) return;
    int c = gid & 15;
    int s = src[e];
    int d = dst[e];
    float v = dis[s] * dis[d] * h[(size_t)s * 16 + c];
    unsafeAtomicAdd(&out[(size_t)d * 16 + c], v);
}

extern "C" void kernel_launch(void* const* d_in, const int* in_sizes, int n_in,
                              void* d_out, int out_size, void* d_ws, size_t ws_size,
                              hipStream_t stream) {
    const float* x  = (const float*)d_in[0];
    const int*   ei = (const int*)d_in[1];        // [2, E] int32
    const float* W1 = (const float*)d_in[2];      // [512,16]
    const float* W2 = (const float*)d_in[3];      // [16,16]
    float* out = (float*)d_out;                   // [N,16]

    const int N = N_NODES;
    const int E = in_sizes[1] / 2;                // 3,200,000
    const int* src = ei;
    const int* dst = ei + E;
    const int B = 256;

    // ---- workspace layout ----
    float* dis  = (float*)d_ws;                   // N
    float* bufA = dis + N;                        // N*16
    float* bufB = bufA + (size_t)N * 16;          // N*16
    int* deg   = (int*)(bufB + (size_t)N * 16);   // N
    int* bcnt  = deg + N;                         // NB
    int* bbase = bcnt + NB;                       // NB+1
    int* cur   = bbase + NB + 1;                  // NB
    unsigned* ebuf = (unsigned*)(cur + NB);       // E
    size_t needed = (size_t)((char*)(ebuf + E) - (char*)d_ws);

    if (ws_size >= needed) {
        // ---- bucketed path ----
        k_zero_i32<<<(N + B - 1) / B, B, 0, stream>>>(deg, N);
        k_hist<<<(E + B - 1) / B, B, 0, stream>>>(dst, deg, E);
        k_dis<<<(N + B - 1) / B, B, 0, stream>>>(deg, dis, N);
        k_bucket_count<<<(NB + B - 1) / B, B, 0, stream>>>(deg, bcnt, N);
        k_scan_buckets<<<1, NB, 0, stream>>>(bcnt, bbase, cur);
        {
            int per = (E + NB - 1) / NB;
            k_partition<<<NB, 256, 0, stream>>>(src, dst, cur, ebuf, E, per);
        }
        k_gemm1<<<(N + 15) / 16, B, 0, stream>>>(x, W1, bufA, N);
        k_agg_bucket<<<NB, 512, 0, stream>>>(ebuf, bbase, dis, bufA, bufB, N);
        k_gemm2<<<(N + 15) / 16, B, 0, stream>>>(bufB, W2, bufA, N);
        k_agg_bucket<<<NB, 512, 0, stream>>>(ebuf, bbase, dis, bufA, out, N);
    } else {
        // ---- fallback: atomic-scatter path ----
        float* fdis = (float*)d_ws;
        float* h1   = fdis + N;
        float* out1 = h1 + (size_t)N * 16;
        float* h2   = out1 + (size_t)N * 16;
        const int NC = N * F_OUT;

        k_deg_init<<<(N + B - 1) / B, B, 0, stream>>>(fdis, N);
        k_deg_count<<<(E + B - 1) / B, B, 0, stream>>>(dst, fdis, E);
        k_rsqrt<<<(N + B - 1) / B, B, 0, stream>>>(fdis, N);

        k_gemm1<<<(N + 15) / 16, B, 0, stream>>>(x, W1, h1, N);
        k_selfloop_init<<<(NC + B - 1) / B, B, 0, stream>>>(fdis, h1, out1, NC);
        {
            long long threads = (long long)E * 16;
            k_scatter<<<(unsigned)((threads + B - 1) / B), B, 0, stream>>>(src, dst, fdis, h1, out1, E);
        }
        k_gemm2<<<(N + 15) / 16, B, 0, stream>>>(out1, W2, h2, N);
        k_selfloop_init<<<(NC + B - 1) / B, B, 0, stream>>>(fdis, h2, out, NC);
        {
            long long threads = (long long)E * 16;
            k_scatter<<<(unsigned)((threads + B - 1) / B), B, 0, stream>>>(src, dst, fdis, h2, out, E);
        }
    }
}

// Round 8
// 1163.070 us; speedup vs baseline: 1.1046x; 1.1046x over previous
//
#include <hip/hip_runtime.h>
#include <hip/hip_bf16.h>

// ---------------------------------------------------------------------------
// 2-layer GCN via dst-range bucketing.
//   deg[i] = 1 + indeg(i);  dis[i] = rsqrt(deg[i])
//   gemm epilogue writes hw[r] = dis[r] * (row @ W)     ("dis-folded")
//   layer: out[i] = dis[i] * ( hw[i] + sum_{e:dst=i} hw[src] )
// Edge partition: 3-pass radix scatter into 512 dst-range buckets
//   (P1 count per (block,bucket) -> P2 offset scan -> P3 scatter).
// Aggregation: per-bucket LDS accumulator (196x17 padded), 1024-thr blocks,
//   4-deep gather unroll, single random load per edge.
// ---------------------------------------------------------------------------

#define N_NODES 100000
#define F_IN 512
#define F_OUT 16
#define NB 512          // buckets == partition grid blocks
#define RNG 196         // nodes per bucket; dst_local fits 8 bits
#define WS_PAD 516      // gemm1 LDS pad

// ---- zero int buffer ------------------------------------------------------
__global__ void k_zero_i32(int* __restrict__ p, int n) {
    int i = blockIdx.x * blockDim.x + threadIdx.x;
    if (i < n) p[i] = 0;
}

// ---- in-degree histogram --------------------------------------------------
__global__ void k_hist(const int* __restrict__ dst, int* __restrict__ deg, int E) {
    int e = blockIdx.x * blockDim.x + threadIdx.x;
    if (e < E) atomicAdd(&deg[dst[e]], 1);
}

// ---- dis = rsqrt(1 + deg) -------------------------------------------------
__global__ void k_dis(const int* __restrict__ deg, float* __restrict__ dis, int n) {
    int i = blockIdx.x * blockDim.x + threadIdx.x;
    if (i < n) dis[i] = rsqrtf(1.0f + (float)deg[i]);
}

// ---- per-bucket edge counts: bcnt[b] = sum deg over node range ------------
__global__ void k_bucket_count(const int* __restrict__ deg, int* __restrict__ bcnt, int n) {
    int b = blockIdx.x * blockDim.x + threadIdx.x;
    if (b >= NB) return;
    int beg = b * RNG, end = min(n, beg + RNG);
    int sum = 0;
    for (int i = beg; i < end; ++i) sum += deg[i];
    bcnt[b] = (beg < n && beg < end) ? sum : 0;
}

// ---- exclusive scan of 512 bucket counts -> bbase[513] --------------------
__global__ __launch_bounds__(512) void k_scan_buckets(const int* __restrict__ bcnt,
                                                      int* __restrict__ bbase) {
    __shared__ int s[NB];
    int i = threadIdx.x;
    int v = bcnt[i];
    s[i] = v;
    __syncthreads();
#pragma unroll
    for (int off = 1; off < NB; off <<= 1) {
        int t = (i >= off) ? s[i - off] : 0;
        __syncthreads();
        s[i] += t;
        __syncthreads();
    }
    bbase[i] = s[i] - v;
    if (i == NB - 1) bbase[NB] = s[NB - 1];   // total = E
}

// ---- P1: per-(block,bucket) histogram -> hgrid[block][bucket] -------------
__global__ __launch_bounds__(512) void k_part_count(const int* __restrict__ dst,
                                                    int* __restrict__ hgrid,
                                                    int E, int per) {
    __shared__ int cnt[NB];
    for (int i = threadIdx.x; i < NB; i += 512) cnt[i] = 0;
    __syncthreads();
    int beg = blockIdx.x * per, end = min(E, beg + per);
    for (int e = beg + threadIdx.x; e < end; e += 512)
        atomicAdd(&cnt[dst[e] / RNG], 1);
    __syncthreads();
    for (int i = threadIdx.x; i < NB; i += 512)
        hgrid[blockIdx.x * NB + i] = cnt[i];
}

// ---- P2: column scan: hgrid[p][b] <- bbase[b] + sum_{p'<p} hgrid[p'][b] ---
// one block of NB threads; thread b walks its column (independent loads).
__global__ __launch_bounds__(512) void k_part_offsets(int* __restrict__ hgrid,
                                                      const int* __restrict__ bbase) {
    int b = threadIdx.x;
    int run = bbase[b];
    for (int p = 0; p < NB; ++p) {
        int t = hgrid[p * NB + b];
        hgrid[p * NB + b] = run;
        run += t;
    }
}

// ---- P3: scatter edges to bucket-clustered ebuf ---------------------------
// entry = src | (dst_local << 17)
__global__ __launch_bounds__(512) void k_part_scatter(const int* __restrict__ src,
                                                      const int* __restrict__ dst,
                                                      const int* __restrict__ hgrid,
                                                      unsigned* __restrict__ ebuf,
                                                      int E, int per) {
    __shared__ int cur[NB];
    for (int i = threadIdx.x; i < NB; i += 512) cur[i] = hgrid[blockIdx.x * NB + i];
    __syncthreads();
    int beg = blockIdx.x * per, end = min(E, beg + per);
    for (int e = beg + threadIdx.x; e < end; e += 512) {
        int d = dst[e];
        int b = d / RNG;
        int slot = atomicAdd(&cur[b], 1);
        ebuf[slot] = (unsigned)src[e] | ((unsigned)(d - b * RNG) << 17);
    }
}

// ---- aggregation: 1024 threads = 64 groups x 16 lanes, 4-deep unroll ------
__global__ __launch_bounds__(1024) void k_agg_bucket(const unsigned* __restrict__ ebuf,
                                                     const int* __restrict__ bbase,
                                                     const float* __restrict__ dis,
                                                     const float* __restrict__ hw,
                                                     float* __restrict__ out, int n) {
    __shared__ float acc[RNG * 17];    // 13.3 KB, stride 17 spreads banks
    for (int i = threadIdx.x; i < RNG * 17; i += 1024) acc[i] = 0.0f;
    __syncthreads();

    int b = blockIdx.x;
    int beg = bbase[b], end = bbase[b + 1];
    int g = threadIdx.x >> 4, l = threadIdx.x & 15;   // 64 groups

    int i0 = beg + g;
    // full quads: issue 4 ebuf reads, then 4 gathers, then 4 LDS atomics
    for (; i0 + 192 < end; i0 += 256) {
        unsigned e0 = ebuf[i0];
        unsigned e1 = ebuf[i0 + 64];
        unsigned e2 = ebuf[i0 + 128];
        unsigned e3 = ebuf[i0 + 192];
        float v0 = hw[(size_t)(e0 & 0x1FFFF) * 16 + l];
        float v1 = hw[(size_t)(e1 & 0x1FFFF) * 16 + l];
        float v2 = hw[(size_t)(e2 & 0x1FFFF) * 16 + l];
        float v3 = hw[(size_t)(e3 & 0x1FFFF) * 16 + l];
        atomicAdd(&acc[(e0 >> 17) * 17 + l], v0);
        atomicAdd(&acc[(e1 >> 17) * 17 + l], v1);
        atomicAdd(&acc[(e2 >> 17) * 17 + l], v2);
        atomicAdd(&acc[(e3 >> 17) * 17 + l], v3);
    }
    for (; i0 < end; i0 += 64) {
        unsigned e0 = ebuf[i0];
        atomicAdd(&acc[(e0 >> 17) * 17 + l], hw[(size_t)(e0 & 0x1FFFF) * 16 + l]);
    }
    __syncthreads();

    // epilogue: out = dis * (hw_self + acc), coalesced
    int base_node = b * RNG;
    for (int nl = g; nl < RNG; nl += 64) {
        int node = base_node + nl;
        if (node < n) {
            size_t o = (size_t)node * 16 + l;
            out[o] = dis[node] * (hw[o] + acc[nl * 17 + l]);
        }
    }
}

// ---- GEMM1: hw[N,16] = dis[r] * (x[N,512] @ W[512,16]), shfl-broadcast ----
__global__ __launch_bounds__(256) void k_gemm1(const float* __restrict__ x,
                                               const float* __restrict__ W,
                                               const float* __restrict__ dis,
                                               float* __restrict__ hw, int nrows) {
    __shared__ __align__(16) float Ws[F_OUT * WS_PAD];  // ~33 KB
    for (int i = threadIdx.x; i < F_IN * F_OUT; i += 256) {
        int k = i >> 4, o = i & 15;
        Ws[o * WS_PAD + k] = W[i];                      // WsT[o][k] = W[k][o]
    }
    __syncthreads();

    int l = threadIdx.x & 15;
    int r = blockIdx.x * 16 + (threadIdx.x >> 4);
    if (r >= nrows) return;

    const float4* xr = (const float4*)(x + (size_t)r * F_IN);
    float4 v[8];
#pragma unroll
    for (int c = 0; c < 8; ++c) v[c] = xr[c * 16 + l];  // coalesced

    const float* wrow = Ws + l * WS_PAD;
    float acc = 0.0f;
#pragma unroll
    for (int c = 0; c < 8; ++c) {
#pragma unroll
        for (int t = 0; t < 16; ++t) {
            float4 wv = *(const float4*)(wrow + c * 64 + t * 4);
            float ax = __shfl(v[c].x, t, 16);
            float ay = __shfl(v[c].y, t, 16);
            float az = __shfl(v[c].z, t, 16);
            float aw = __shfl(v[c].w, t, 16);
            acc = fmaf(ax, wv.x, acc);
            acc = fmaf(ay, wv.y, acc);
            acc = fmaf(az, wv.z, acc);
            acc = fmaf(aw, wv.w, acc);
        }
    }
    hw[(size_t)r * 16 + l] = dis[r] * acc;
}

// ---- GEMM2: hw2[N,16] = dis[r] * (a[N,16] @ W2[16,16]) --------------------
__global__ __launch_bounds__(256) void k_gemm2(const float* __restrict__ a,
                                               const float* __restrict__ W,
                                               const float* __restrict__ dis,
                                               float* __restrict__ hw2, int nrows) {
    __shared__ float Ws[F_OUT * 17];
    if (threadIdx.x < 256) {
        int i = threadIdx.x;
        int k = i >> 4, o = i & 15;
        Ws[o * 17 + k] = W[i];
    }
    __syncthreads();
    int l = threadIdx.x & 15;
    int r = blockIdx.x * 16 + (threadIdx.x >> 4);
    if (r >= nrows) return;
    float av = a[(size_t)r * 16 + l];
    const float* wrow = Ws + l * 17;
    float acc = 0.0f;
#pragma unroll
    for (int t = 0; t < 16; ++t) {
        float xv = __shfl(av, t, 16);
        acc = fmaf(xv, wrow[t], acc);
    }
    hw2[(size_t)r * 16 + l] = dis[r] * acc;
}

// ---------------- fallback path (atomic scatter), proven correct -----------
__global__ void k_deg_init(float* __restrict__ deg, int n) {
    int i = blockIdx.x * blockDim.x + threadIdx.x;
    if (i < n) deg[i] = 1.0f;
}
__global__ void k_deg_count(const int* __restrict__ dst, float* __restrict__ deg, int E) {
    int e = blockIdx.x * blockDim.x + threadIdx.x;
    if (e < E) unsafeAtomicAdd(&deg[dst[e]], 1.0f);
}
__global__ void k_rsqrt(float* __restrict__ deg, int n) {
    int i = blockIdx.x * blockDim.x + threadIdx.x;
    if (i < n) deg[i] = rsqrtf(deg[i]);
}
__global__ void k_selfloop_init(const float* __restrict__ dis, const float* __restrict__ h,
                                float* __restrict__ out, int total) {
    int t = blockIdx.x * blockDim.x + threadIdx.x;
    if (t >= total) return;
    int i = t >> 4;
    float d = dis[i];
    out[t] = d * h[t];   // h here is dis-folded hw: d*hw = d*d*h_raw
}
__global__ __launch_bounds__(256) void k_scatter(const int* __restrict__ src,
                                                 const int* __restrict__ dst,
                                                 const float* __restrict__ dis,
                                                 const float* __restrict__ hw,
                                                 float* __restrict__ out, int E) {
    int gid = blockIdx.x * 256 + threadIdx.x;
    int e = gid >> 4;
    if (e >= E) return;
    int c = gid & 15;
    int s = src[e];
    int d = dst[e];
    float v = dis[d] * hw[(size_t)s * 16 + c];   // dis[s] folded in hw
    unsafeAtomicAdd(&out[(size_t)d * 16 + c], v);
}

extern "C" void kernel_launch(void* const* d_in, const int* in_sizes, int n_in,
                              void* d_out, int out_size, void* d_ws, size_t ws_size,
                              hipStream_t stream) {
    const float* x  = (const float*)d_in[0];
    const int*   ei = (const int*)d_in[1];        // [2, E] int32
    const float* W1 = (const float*)d_in[2];      // [512,16]
    const float* W2 = (const float*)d_in[3];      // [16,16]
    float* out = (float*)d_out;                   // [N,16]

    const int N = N_NODES;
    const int E = in_sizes[1] / 2;                // 3,200,000
    const int* src = ei;
    const int* dst = ei + E;
    const int B = 256;
    const int per = (E + NB - 1) / NB;            // edges per partition block

    // ---- workspace layout ----
    float* dis  = (float*)d_ws;                   // N
    float* bufA = dis + N;                        // N*16  (hw1, then hw2)
    float* bufB = bufA + (size_t)N * 16;          // N*16  (out1)
    int* deg   = (int*)(bufB + (size_t)N * 16);   // N
    int* bcnt  = deg + N;                         // NB
    int* bbase = bcnt + NB;                       // NB+1
    int* hgrid = bbase + NB + 1;                  // NB*NB
    unsigned* ebuf = (unsigned*)(hgrid + NB * NB);// E
    size_t needed = (size_t)((char*)(ebuf + E) - (char*)d_ws);

    if (ws_size >= needed) {
        // ---- bucketed path ----
        k_zero_i32<<<(N + B - 1) / B, B, 0, stream>>>(deg, N);
        k_hist<<<(E + B - 1) / B, B, 0, stream>>>(dst, deg, E);
        k_dis<<<(N + B - 1) / B, B, 0, stream>>>(deg, dis, N);
        k_bucket_count<<<(NB + B - 1) / B, B, 0, stream>>>(deg, bcnt, N);
        k_scan_buckets<<<1, NB, 0, stream>>>(bcnt, bbase);
        k_part_count<<<NB, 512, 0, stream>>>(dst, hgrid, E, per);
        k_part_offsets<<<1, NB, 0, stream>>>(hgrid, bbase);
        k_part_scatter<<<NB, 512, 0, stream>>>(src, dst, hgrid, ebuf, E, per);

        k_gemm1<<<(N + 15) / 16, B, 0, stream>>>(x, W1, dis, bufA, N);
        k_agg_bucket<<<NB, 1024, 0, stream>>>(ebuf, bbase, dis, bufA, bufB, N);
        k_gemm2<<<(N + 15) / 16, B, 0, stream>>>(bufB, W2, dis, bufA, N);
        k_agg_bucket<<<NB, 1024, 0, stream>>>(ebuf, bbase, dis, bufA, out, N);
    } else {
        // ---- fallback: atomic-scatter path (dis-folded variants) ----
        float* fdis = (float*)d_ws;
        float* h1   = fdis + N;
        float* out1 = h1 + (size_t)N * 16;
        float* h2   = out1 + (size_t)N * 16;
        const int NC = N * F_OUT;

        k_deg_init<<<(N + B - 1) / B, B, 0, stream>>>(fdis, N);
        k_deg_count<<<(E + B - 1) / B, B, 0, stream>>>(dst, fdis, E);
        k_rsqrt<<<(N + B - 1) / B, B, 0, stream>>>(fdis, N);

        k_gemm1<<<(N + 15) / 16, B, 0, stream>>>(x, W1, fdis, h1, N);
        k_selfloop_init<<<(NC + B - 1) / B, B, 0, stream>>>(fdis, h1, out1, NC);
        {
            long long threads = (long long)E * 16;
            k_scatter<<<(unsigned)((threads + B - 1) / B), B, 0, stream>>>(src, dst, fdis, h1, out1, E);
        }
        k_gemm2<<<(N + 15) / 16, B, 0, stream>>>(out1, W2, fdis, h2, N);
        k_selfloop_init<<<(NC + B - 1) / B, B, 0, stream>>>(fdis, h2, out, NC);
        {
            long long threads = (long long)E * 16;
            k_scatter<<<(unsigned)((threads + B - 1) / B), B, 0, stream>>>(src, dst, fdis, h2, out, E);
        }
    }
}

// Round 9
// 861.343 us; speedup vs baseline: 1.4915x; 1.3503x over previous
//
#include <hip/hip_runtime.h>
#include <hip/hip_bf16.h>

// ---------------------------------------------------------------------------
// 2-layer GCN, push-scatter formulation (round-5 structure, leaned down):
//   deg[i] = 1 + indeg(i);  dis[i] = rsqrt(deg[i])
//   gemm epilogue: hw[r] = dis[r] * (row @ W)   and also inits accumulator
//   scatter:       accum[d] += hw[s]            (hw gather + global f32 atomics)
//   defer dis[d]:  layer-1's dis[d] folds into gemm2's row load;
//                  layer-2's dis[d] is one tiny final scale pass.
//   out = dis .* (hw2 + scatter-sum(hw2))
// ---------------------------------------------------------------------------

#define N_NODES 100000
#define F_IN 512
#define F_OUT 16
#define WS_PAD 516      // W1 LDS leading-dim pad (2-way max bank alias)

// ---- zero int buffer ------------------------------------------------------
__global__ void k_zero_i32(int* __restrict__ p, int n) {
    int i = blockIdx.x * blockDim.x + threadIdx.x;
    if (i < n) p[i] = 0;
}

// ---- in-degree histogram --------------------------------------------------
__global__ void k_hist(const int* __restrict__ dst, int* __restrict__ deg, int E) {
    int e = blockIdx.x * blockDim.x + threadIdx.x;
    if (e < E) atomicAdd(&deg[dst[e]], 1);
}

// ---- dis = rsqrt(1 + deg) -------------------------------------------------
__global__ void k_dis(const int* __restrict__ deg, float* __restrict__ dis, int n) {
    int i = blockIdx.x * blockDim.x + threadIdx.x;
    if (i < n) dis[i] = rsqrtf(1.0f + (float)deg[i]);
}

// ---- GEMM1: hw[N,16] = dis[r]*(x[N,512] @ W[512,16]); dual-store ----------
// 512 thr = 32 rows/block (W-stage amortized), x in two 4xfloat4 halves
// (~50 VGPR -> 8 waves/SIMD), dual accumulators to split the FMA dep chain.
__global__ __launch_bounds__(512, 8) void k_gemm1(const float* __restrict__ x,
                                                  const float* __restrict__ W,
                                                  const float* __restrict__ dis,
                                                  float* __restrict__ hw,
                                                  float* __restrict__ accum,
                                                  int nrows) {
    __shared__ __align__(16) float Ws[F_OUT * WS_PAD];  // ~33 KB
    for (int i = threadIdx.x; i < F_IN * F_OUT; i += 512) {
        int k = i >> 4, o = i & 15;
        Ws[o * WS_PAD + k] = W[i];                      // WsT[o][k] = W[k][o]
    }
    __syncthreads();

    int l = threadIdx.x & 15;
    int r = blockIdx.x * 32 + (threadIdx.x >> 4);
    if (r >= nrows) return;

    const float4* xr = (const float4*)(x + (size_t)r * F_IN);
    const float* wrow = Ws + l * WS_PAD;
    float acc0 = 0.0f, acc1 = 0.0f;

#pragma unroll
    for (int half = 0; half < 2; ++half) {
        float4 v0 = xr[half * 64 + 0 * 16 + l];         // coalesced 256B/group
        float4 v1 = xr[half * 64 + 1 * 16 + l];
        float4 v2 = xr[half * 64 + 2 * 16 + l];
        float4 v3 = xr[half * 64 + 3 * 16 + l];
        const float* wb = wrow + half * 256;
#pragma unroll
        for (int t = 0; t < 16; ++t) {
            float4 wa = *(const float4*)(wb + t * 4);            // cc=0
            float4 wc = *(const float4*)(wb + 64 + t * 4);       // cc=1
            acc0 = fmaf(__shfl(v0.x, t, 16), wa.x, acc0);
            acc0 = fmaf(__shfl(v0.y, t, 16), wa.y, acc0);
            acc0 = fmaf(__shfl(v0.z, t, 16), wa.z, acc0);
            acc0 = fmaf(__shfl(v0.w, t, 16), wa.w, acc0);
            acc1 = fmaf(__shfl(v1.x, t, 16), wc.x, acc1);
            acc1 = fmaf(__shfl(v1.y, t, 16), wc.y, acc1);
            acc1 = fmaf(__shfl(v1.z, t, 16), wc.z, acc1);
            acc1 = fmaf(__shfl(v1.w, t, 16), wc.w, acc1);
        }
#pragma unroll
        for (int t = 0; t < 16; ++t) {
            float4 wa = *(const float4*)(wb + 128 + t * 4);      // cc=2
            float4 wc = *(const float4*)(wb + 192 + t * 4);      // cc=3
            acc0 = fmaf(__shfl(v2.x, t, 16), wa.x, acc0);
            acc0 = fmaf(__shfl(v2.y, t, 16), wa.y, acc0);
            acc0 = fmaf(__shfl(v2.z, t, 16), wa.z, acc0);
            acc0 = fmaf(__shfl(v2.w, t, 16), wa.w, acc0);
            acc1 = fmaf(__shfl(v3.x, t, 16), wc.x, acc1);
            acc1 = fmaf(__shfl(v3.y, t, 16), wc.y, acc1);
            acc1 = fmaf(__shfl(v3.z, t, 16), wc.z, acc1);
            acc1 = fmaf(__shfl(v3.w, t, 16), wc.w, acc1);
        }
    }
    float hv = dis[r] * (acc0 + acc1);
    size_t o = (size_t)r * 16 + l;
    hw[o] = hv;
    accum[o] = hv;      // self-loop term == accumulator init (no memset)
}

// ---- GEMM2: hw2 = dis[r]*((dis[r]*S1[r]) @ W2); dual-store ----------------
// input S1 = accum from layer 1 (unscaled); dis[r] folds the deferred scale.
__global__ __launch_bounds__(256) void k_gemm2(const float* __restrict__ S1,
                                               const float* __restrict__ W,
                                               const float* __restrict__ dis,
                                               float* __restrict__ hw2,
                                               float* __restrict__ accum,
                                               int nrows) {
    __shared__ float Ws[F_OUT * 17];
    if (threadIdx.x < 256) {
        int i = threadIdx.x;
        int k = i >> 4, o = i & 15;
        Ws[o * 17 + k] = W[i];
    }
    __syncthreads();
    int l = threadIdx.x & 15;
    int r = blockIdx.x * 16 + (threadIdx.x >> 4);
    if (r >= nrows) return;
    float dr = dis[r];
    float av = dr * S1[(size_t)r * 16 + l];             // deferred layer-1 dis[d]
    const float* wrow = Ws + l * 17;
    float acc = 0.0f;
#pragma unroll
    for (int t = 0; t < 16; ++t) {
        float xv = __shfl(av, t, 16);
        acc = fmaf(xv, wrow[t], acc);
    }
    float hv = dr * acc;
    size_t o = (size_t)r * 16 + l;
    hw2[o] = hv;
    accum[o] = hv;      // init d_out accumulator
}

// ---- push scatter: accum[dst] += hw[src], 16 lanes per edge ---------------
__global__ __launch_bounds__(256) void k_scatter(const int* __restrict__ src,
                                                 const int* __restrict__ dst,
                                                 const float* __restrict__ hw,
                                                 float* __restrict__ accum, int E) {
    int gid = blockIdx.x * 256 + threadIdx.x;
    int e = gid >> 4;
    if (e >= E) return;
    int c = gid & 15;
    int s = src[e];                                    // broadcast in group
    int d = dst[e];
    float v = hw[(size_t)s * 16 + c];                  // 64B coalesced gather
    unsafeAtomicAdd(&accum[(size_t)d * 16 + c], v);    // hw global_atomic_add_f32
}

// ---- final: out[i,c] *= dis[i]  (deferred layer-2 dis[d]) -----------------
__global__ void k_scale(float* __restrict__ out, const float* __restrict__ dis, int total) {
    int t = blockIdx.x * blockDim.x + threadIdx.x;
    if (t >= total) return;
    out[t] *= dis[t >> 4];
}

extern "C" void kernel_launch(void* const* d_in, const int* in_sizes, int n_in,
                              void* d_out, int out_size, void* d_ws, size_t ws_size,
                              hipStream_t stream) {
    const float* x  = (const float*)d_in[0];
    const int*   ei = (const int*)d_in[1];        // [2, E] int32
    const float* W1 = (const float*)d_in[2];      // [512,16]
    const float* W2 = (const float*)d_in[3];      // [16,16]
    float* out = (float*)d_out;                   // [N,16]

    const int N = N_NODES;
    const int E = in_sizes[1] / 2;                // 3,200,000
    const int* src = ei;
    const int* dst = ei + E;
    const int B = 256;
    const int NC = N * F_OUT;

    // ---- workspace layout (~13.6 MB) ----
    float* dis  = (float*)d_ws;                   // N
    float* bufA = dis + N;                        // N*16  hw1, then hw2
    float* bufB = bufA + (size_t)N * 16;          // N*16  S1 accumulator
    int*   deg  = (int*)(bufB + (size_t)N * 16);  // N

    // degree + norm (shared by both layers)
    k_zero_i32<<<(N + B - 1) / B, B, 0, stream>>>(deg, N);
    k_hist<<<(E + B - 1) / B, B, 0, stream>>>(dst, deg, E);
    k_dis<<<(N + B - 1) / B, B, 0, stream>>>(deg, dis, N);

    // layer 1: hw1 = dis.*(x@W1); S1 = hw1 + scatter(hw1)
    k_gemm1<<<(N + 31) / 32, 512, 0, stream>>>(x, W1, dis, bufA, bufB, N);
    {
        long long threads = (long long)E * 16;
        k_scatter<<<(unsigned)((threads + B - 1) / B), B, 0, stream>>>(src, dst, bufA, bufB, E);
    }

    // layer 2: hw2 = dis.*((dis.*S1)@W2); out = dis.*(hw2 + scatter(hw2))
    k_gemm2<<<(N + 15) / 16, B, 0, stream>>>(bufB, W2, dis, bufA, out, N);
    {
        long long threads = (long long)E * 16;
        k_scatter<<<(unsigned)((threads + B - 1) / B), B, 0, stream>>>(src, dst, bufA, out, E);
    }
    k_scale<<<(NC + B - 1) / B, B, 0, stream>>>(out, dis, NC);
}

// Round 10
// 801.420 us; speedup vs baseline: 1.6030x; 1.0748x over previous
//
#include <hip/hip_runtime.h>
#include <hip/hip_bf16.h>

// ---------------------------------------------------------------------------
// 2-layer GCN, push-scatter formulation:
//   deg[i] = 1 + indeg(i);  dis[i] = rsqrt(deg[i])
//   gemm epilogue: hw[r] = dis[r] * (row @ W)   and also inits accumulator
//   scatter:       accum[d] += hw[s]            (hw gather + global f32 atomics)
//   defer dis[d]:  layer-1's dis[d] folds into gemm2's row load;
//                  layer-2's dis[d] is one tiny final scale pass.
//   out = dis .* (hw2 + scatter-sum(hw2))
// gemm1: 2 threads/row, x streamed in registers, W rows read via
// wave-UNIFORM ds_read_b128 broadcasts (no shfl, no divergent LDS).
// ---------------------------------------------------------------------------

#define N_NODES 100000
#define F_IN 512
#define F_OUT 16

// ---- zero int buffer ------------------------------------------------------
__global__ void k_zero_i32(int* __restrict__ p, int n) {
    int i = blockIdx.x * blockDim.x + threadIdx.x;
    if (i < n) p[i] = 0;
}

// ---- in-degree histogram --------------------------------------------------
__global__ void k_hist(const int* __restrict__ dst, int* __restrict__ deg, int E) {
    int e = blockIdx.x * blockDim.x + threadIdx.x;
    if (e < E) atomicAdd(&deg[dst[e]], 1);
}

// ---- dis = rsqrt(1 + deg) -------------------------------------------------
__global__ void k_dis(const int* __restrict__ deg, float* __restrict__ dis, int n) {
    int i = blockIdx.x * blockDim.x + threadIdx.x;
    if (i < n) dis[i] = rsqrtf(1.0f + (float)deg[i]);
}

// ---- GEMM1: hw[N,16] = dis[r]*(x[N,512] @ W[512,16]); dual-store ----------
// thread t -> (row r = t>>1, half h = t&1). Each thread: K-half of 256,
// 16 reg accumulators, W[k][0..15] via uniform ds_read_b128 (broadcast).
// Pair-reduce with __shfl_xor(.,1); lane h writes cols h*8..h*8+7.
__global__ __launch_bounds__(256) void k_gemm1(const float* __restrict__ x,
                                               const float* __restrict__ W,
                                               const float* __restrict__ dis,
                                               float* __restrict__ hw,
                                               float* __restrict__ accum,
                                               int nrows) {
    __shared__ __align__(16) float Ws[F_IN * F_OUT];   // 32 KB, same layout as W
    {
        const float4* Wg = (const float4*)W;
        float4* Ws4 = (float4*)Ws;
        for (int i = threadIdx.x; i < (F_IN * F_OUT) / 4; i += 256) Ws4[i] = Wg[i];
    }
    __syncthreads();

    int t = blockIdx.x * 256 + threadIdx.x;
    int r = t >> 1;
    int h = t & 1;
    if (r >= nrows) return;

    const float4* xr = (const float4*)(x + (size_t)r * F_IN) + h * 64;  // my K-half
    const float4* Wb = (const float4*)Ws + h * 1024;                    // k = h*256 ...

    float acc[16];
#pragma unroll
    for (int o = 0; o < 16; ++o) acc[o] = 0.0f;

    for (int c = 0; c < 16; ++c) {                 // chunks of 16 k (one 64B line)
        float4 xv0 = xr[c * 4 + 0];
        float4 xv1 = xr[c * 4 + 1];
        float4 xv2 = xr[c * 4 + 2];
        float4 xv3 = xr[c * 4 + 3];
        float xa[16] = {xv0.x, xv0.y, xv0.z, xv0.w,
                        xv1.x, xv1.y, xv1.z, xv1.w,
                        xv2.x, xv2.y, xv2.z, xv2.w,
                        xv3.x, xv3.y, xv3.z, xv3.w};
        const float4* wk = Wb + c * 64;            // 16 k-rows x 4 float4
#pragma unroll
        for (int kk = 0; kk < 16; ++kk) {
            float4 w0 = wk[kk * 4 + 0];            // uniform addr -> broadcast
            float4 w1 = wk[kk * 4 + 1];
            float4 w2 = wk[kk * 4 + 2];
            float4 w3 = wk[kk * 4 + 3];
            float xk = xa[kk];
            acc[0]  = fmaf(xk, w0.x, acc[0]);
            acc[1]  = fmaf(xk, w0.y, acc[1]);
            acc[2]  = fmaf(xk, w0.z, acc[2]);
            acc[3]  = fmaf(xk, w0.w, acc[3]);
            acc[4]  = fmaf(xk, w1.x, acc[4]);
            acc[5]  = fmaf(xk, w1.y, acc[5]);
            acc[6]  = fmaf(xk, w1.z, acc[6]);
            acc[7]  = fmaf(xk, w1.w, acc[7]);
            acc[8]  = fmaf(xk, w2.x, acc[8]);
            acc[9]  = fmaf(xk, w2.y, acc[9]);
            acc[10] = fmaf(xk, w2.z, acc[10]);
            acc[11] = fmaf(xk, w2.w, acc[11]);
            acc[12] = fmaf(xk, w3.x, acc[12]);
            acc[13] = fmaf(xk, w3.y, acc[13]);
            acc[14] = fmaf(xk, w3.z, acc[14]);
            acc[15] = fmaf(xk, w3.w, acc[15]);
        }
    }

    // combine the two K-halves (lane pairs 2i <-> 2i+1)
#pragma unroll
    for (int o = 0; o < 16; ++o) acc[o] += __shfl_xor(acc[o], 1);

    float dr = dis[r];
    float s0 = h ? acc[8]  : acc[0];
    float s1 = h ? acc[9]  : acc[1];
    float s2 = h ? acc[10] : acc[2];
    float s3 = h ? acc[11] : acc[3];
    float s4 = h ? acc[12] : acc[4];
    float s5 = h ? acc[13] : acc[5];
    float s6 = h ? acc[14] : acc[6];
    float s7 = h ? acc[15] : acc[7];
    float4 p0 = make_float4(dr * s0, dr * s1, dr * s2, dr * s3);
    float4 p1 = make_float4(dr * s4, dr * s5, dr * s6, dr * s7);
    size_t base = (size_t)r * 16 + h * 8;
    *(float4*)(hw + base)        = p0;
    *(float4*)(hw + base + 4)    = p1;
    *(float4*)(accum + base)     = p0;   // self-loop term == accumulator init
    *(float4*)(accum + base + 4) = p1;
}

// ---- GEMM2: hw2 = dis[r]*((dis[r]*S1[r]) @ W2); dual-store ----------------
__global__ __launch_bounds__(256) void k_gemm2(const float* __restrict__ S1,
                                               const float* __restrict__ W,
                                               const float* __restrict__ dis,
                                               float* __restrict__ hw2,
                                               float* __restrict__ accum,
                                               int nrows) {
    __shared__ float Ws[F_OUT * 17];
    if (threadIdx.x < 256) {
        int i = threadIdx.x;
        int k = i >> 4, o = i & 15;
        Ws[o * 17 + k] = W[i];
    }
    __syncthreads();
    int l = threadIdx.x & 15;
    int r = blockIdx.x * 16 + (threadIdx.x >> 4);
    if (r >= nrows) return;
    float dr = dis[r];
    float av = dr * S1[(size_t)r * 16 + l];             // deferred layer-1 dis[d]
    const float* wrow = Ws + l * 17;
    float acc = 0.0f;
#pragma unroll
    for (int t = 0; t < 16; ++t) {
        float xv = __shfl(av, t, 16);
        acc = fmaf(xv, wrow[t], acc);
    }
    float hv = dr * acc;
    size_t o = (size_t)r * 16 + l;
    hw2[o] = hv;
    accum[o] = hv;      // init d_out accumulator
}

// ---- push scatter: accum[dst] += hw[src], 16 lanes per edge ---------------
__global__ __launch_bounds__(256) void k_scatter(const int* __restrict__ src,
                                                 const int* __restrict__ dst,
                                                 const float* __restrict__ hw,
                                                 float* __restrict__ accum, int E) {
    int gid = blockIdx.x * 256 + threadIdx.x;
    int e = gid >> 4;
    if (e >= E) return;
    int c = gid & 15;
    int s = src[e];                                    // broadcast in group
    int d = dst[e];
    float v = hw[(size_t)s * 16 + c];                  // 64B coalesced gather
    unsafeAtomicAdd(&accum[(size_t)d * 16 + c], v);    // hw global_atomic_add_f32
}

// ---- final: out[i,c] *= dis[i]  (deferred layer-2 dis[d]) -----------------
__global__ void k_scale(float* __restrict__ out, const float* __restrict__ dis, int total) {
    int t = blockIdx.x * blockDim.x + threadIdx.x;
    if (t >= total) return;
    out[t] *= dis[t >> 4];
}

extern "C" void kernel_launch(void* const* d_in, const int* in_sizes, int n_in,
                              void* d_out, int out_size, void* d_ws, size_t ws_size,
                              hipStream_t stream) {
    const float* x  = (const float*)d_in[0];
    const int*   ei = (const int*)d_in[1];        // [2, E] int32
    const float* W1 = (const float*)d_in[2];      // [512,16]
    const float* W2 = (const float*)d_in[3];      // [16,16]
    float* out = (float*)d_out;                   // [N,16]

    const int N = N_NODES;
    const int E = in_sizes[1] / 2;                // 3,200,000
    const int* src = ei;
    const int* dst = ei + E;
    const int B = 256;
    const int NC = N * F_OUT;

    // ---- workspace layout (~13.6 MB) ----
    float* dis  = (float*)d_ws;                   // N
    float* bufA = dis + N;                        // N*16  hw1, then hw2
    float* bufB = bufA + (size_t)N * 16;          // N*16  S1 accumulator
    int*   deg  = (int*)(bufB + (size_t)N * 16);  // N

    // degree + norm (shared by both layers)
    k_zero_i32<<<(N + B - 1) / B, B, 0, stream>>>(deg, N);
    k_hist<<<(E + B - 1) / B, B, 0, stream>>>(dst, deg, E);
    k_dis<<<(N + B - 1) / B, B, 0, stream>>>(deg, dis, N);

    // layer 1: hw1 = dis.*(x@W1); S1 = hw1 + scatter(hw1)
    k_gemm1<<<(2 * N + 255) / 256, 256, 0, stream>>>(x, W1, dis, bufA, bufB, N);
    {
        long long threads = (long long)E * 16;
        k_scatter<<<(unsigned)((threads + B - 1) / B), B, 0, stream>>>(src, dst, bufA, bufB, E);
    }

    // layer 2: hw2 = dis.*((dis.*S1)@W2); out = dis.*(hw2 + scatter(hw2))
    k_gemm2<<<(N + 15) / 16, B, 0, stream>>>(bufB, W2, dis, bufA, out, N);
    {
        long long threads = (long long)E * 16;
        k_scatter<<<(unsigned)((threads + B - 1) / B), B, 0, stream>>>(src, dst, bufA, out, E);
    }
    k_scale<<<(NC + B - 1) / B, B, 0, stream>>>(out, dis, NC);
}